// Round 1
// baseline (799.305 us; speedup 1.0000x reference)
//
#include <hip/hip_runtime.h>
#include <math.h>

#define NN 50000
#define EE 800000
#define ET 850000    // EE + NN self loops
#define FIN 128
#define HD 64
#define NH 4
#define NGR 64
#define NCL 10
#define NEG 0.2f

__device__ __forceinline__ float lrelu(float x){ return x > 0.f ? x : NEG * x; }

__device__ __forceinline__ float wsum(float v){
#pragma unroll
  for (int o = 32; o > 0; o >>= 1) v += __shfl_xor(v, o, 64);
  return v;
}
__device__ __forceinline__ float wmax(float v){
#pragma unroll
  for (int o = 32; o > 0; o >>= 1) v = fmaxf(v, __shfl_xor(v, o, 64));
  return v;
}
__device__ __forceinline__ int esrc(const int* ei, int e){ return e < EE ? ei[e] : e - EE; }
__device__ __forceinline__ int edst(const int* ei, int e){ return e < EE ? ei[EE + e] : e - EE; }

// monotonic float<->uint key (total order preserved); key 0 < all finite floats
__device__ __forceinline__ unsigned f2key(float f){
  unsigned u = __float_as_uint(f);
  return (u & 0x80000000u) ? ~u : (u | 0x80000000u);
}
__device__ __forceinline__ float key2f(unsigned k){
  return (k & 0x80000000u) ? __uint_as_float(k & 0x7fffffffu) : __uint_as_float(~k);
}

// ---------- dense kernels ----------

// h0 = relu(x @ W_proj + b_proj)   [NN,128]@[128,64]
__global__ void k_proj(const float* __restrict__ x, const float* __restrict__ Wp,
                       const float* __restrict__ bp, float* __restrict__ h0){
  int n = blockIdx.x, j = threadIdx.x;   // 64 threads
  __shared__ float xs[FIN];
  xs[j] = x[n*FIN + j];
  xs[j+64] = x[n*FIN + 64 + j];
  __syncthreads();
  float acc = bp[j];
#pragma unroll 16
  for (int k = 0; k < FIN; ++k) acc += xs[k] * Wp[k*HD + j];
  h0[n*HD + j] = acc > 0.f ? acc : 0.f;
}

// h1feat = h0 @ W1  [NN,64]@[64,256];  a_src1/a_dst1 = per-head att dots
__global__ void k_feat1(const float* __restrict__ h0, const float* __restrict__ W1,
                        const float* __restrict__ as, const float* __restrict__ ad,
                        float* __restrict__ h1feat, float* __restrict__ a_s, float* __restrict__ a_d){
  int n = blockIdx.x, j = threadIdx.x;   // 256 threads
  __shared__ float hs[HD];
  if (j < HD) hs[j] = h0[n*HD + j];
  __syncthreads();
  float acc = 0.f;
#pragma unroll 16
  for (int k = 0; k < HD; ++k) acc += hs[k] * W1[k*256 + j];
  h1feat[n*256 + j] = acc;
  int h = j >> 6, lane = j & 63;
  float vs = wsum(acc * as[j]);
  float vd = wsum(acc * ad[j]);
  if (lane == 0){ a_s[n*NH + h] = vs; a_d[n*NH + h] = vd; }
}

// h2feat = h1out @ W2  [NN,256]@[256,64];  a_src2/a_dst2
__global__ void k_feat2(const float* __restrict__ h1out, const float* __restrict__ W2,
                        const float* __restrict__ as, const float* __restrict__ ad,
                        float* __restrict__ h2feat, float* __restrict__ a_s, float* __restrict__ a_d){
  int n = blockIdx.x, j = threadIdx.x;   // 64 threads
  __shared__ float hs[256];
#pragma unroll
  for (int k = j; k < 256; k += 64) hs[k] = h1out[n*256 + k];
  __syncthreads();
  float acc = 0.f;
#pragma unroll 16
  for (int k = 0; k < 256; ++k) acc += hs[k] * W2[k*HD + j];
  h2feat[n*HD + j] = acc;
  float vs = wsum(acc * as[j]);
  float vd = wsum(acc * ad[j]);
  if (j == 0){ a_s[n] = vs; a_d[n] = vd; }
}

// ---------- CSR build ----------

__global__ void k_hist(const int* __restrict__ ei, int* __restrict__ cnt){
  int e = blockIdx.x*256 + threadIdx.x;
  if (e < ET) atomicAdd(&cnt[edst(ei, e)], 1);
}

__global__ void k_bsum(const int* __restrict__ cnt, int* __restrict__ bsums){
  int b = blockIdx.x, t = threadIdx.x;
  int i = b*256 + t;
  int v = (i < NN) ? cnt[i] : 0;
  float s = wsum((float)v);
  __shared__ float ws4[4];
  if ((t & 63) == 0) ws4[t >> 6] = s;
  __syncthreads();
  if (t == 0) bsums[b] = (int)(ws4[0] + ws4[1] + ws4[2] + ws4[3] + 0.5f);
}

__global__ void k_boff(const int* __restrict__ bsums, int* __restrict__ boffs, int nb){
  if (threadIdx.x == 0){
    int r = 0;
    for (int b = 0; b < nb; ++b){ boffs[b] = r; r += bsums[b]; }
  }
}

__global__ void k_off(const int* __restrict__ cnt, const int* __restrict__ boffs,
                      int* __restrict__ off, int* __restrict__ pos){
  int b = blockIdx.x, t = threadIdx.x;
  int i = b*256 + t;
  __shared__ int s[256];
  int v = (i < NN) ? cnt[i] : 0;
  s[t] = v; __syncthreads();
  for (int d = 1; d < 256; d <<= 1){
    int xv = (t >= d) ? s[t-d] : 0;
    __syncthreads();
    s[t] += xv;
    __syncthreads();
  }
  int excl = s[t] - v;
  if (i < NN){ int o = boffs[b] + excl; off[i] = o; pos[i] = o; }
  if (i == NN - 1) off[NN] = boffs[b] + s[t];
}

__global__ void k_scatter(const int* __restrict__ ei, int* __restrict__ pos, int* __restrict__ eids){
  int e = blockIdx.x*256 + threadIdx.x;
  if (e < ET){
    int d = edst(ei, e);
    int idx = atomicAdd(&pos[d], 1);
    eids[idx] = e;
  }
}

// ---------- GAT aggregation (block per dst node) ----------

__global__ void k_gat1(const float* __restrict__ h1feat, const float* __restrict__ a_s,
                       const float* __restrict__ a_d, const int* __restrict__ off,
                       const int* __restrict__ eids, const int* __restrict__ ei,
                       const float* __restrict__ b1, float* __restrict__ h1out){
  int n = blockIdx.x;
  int h = threadIdx.x >> 6, lane = threadIdx.x & 63;   // 256 threads = 4 waves = 4 heads
  int e0 = off[n], e1 = off[n+1];
  float adst = a_d[n*NH + h];
  float m = -3.0e38f;
  for (int i = e0 + lane; i < e1; i += 64){
    int s = esrc(ei, eids[i]);
    m = fmaxf(m, lrelu(a_s[s*NH + h] + adst));
  }
  m = wmax(m);
  float se = 0.f;
  for (int i = e0 + lane; i < e1; i += 64){
    int s = esrc(ei, eids[i]);
    se += expf(lrelu(a_s[s*NH + h] + adst) - m);
  }
  se = wsum(se);
  float inv = 1.f / (se + 1e-16f);
  float acc = 0.f;
  for (int i = e0; i < e1; ++i){
    int s = esrc(ei, eids[i]);
    float w = expf(lrelu(a_s[s*NH + h] + adst) - m) * inv;
    acc += h1feat[s*256 + h*64 + lane] * w;
  }
  float o = acc + b1[h*64 + lane];
  h1out[n*256 + h*64 + lane] = lrelu(o);
}

__global__ void k_gat2(const float* __restrict__ h2feat, const float* __restrict__ a_s,
                       const float* __restrict__ a_d, const int* __restrict__ off,
                       const int* __restrict__ eids, const int* __restrict__ ei,
                       const float* __restrict__ b2, float* __restrict__ h2out){
  int n = blockIdx.x;
  int lane = threadIdx.x;   // 64 threads
  int e0 = off[n], e1 = off[n+1];
  float adst = a_d[n];
  float m = -3.0e38f;
  for (int i = e0 + lane; i < e1; i += 64){
    int s = esrc(ei, eids[i]);
    m = fmaxf(m, lrelu(a_s[s] + adst));
  }
  m = wmax(m);
  float se = 0.f;
  for (int i = e0 + lane; i < e1; i += 64){
    int s = esrc(ei, eids[i]);
    se += expf(lrelu(a_s[s] + adst) - m);
  }
  se = wsum(se);
  float inv = 1.f / (se + 1e-16f);
  float acc = 0.f;
  for (int i = e0; i < e1; ++i){
    int s = esrc(ei, eids[i]);
    float w = expf(lrelu(a_s[s] + adst) - m) * inv;
    acc += h2feat[s*HD + lane] * w;
  }
  float o = acc + b2[lane];
  h2out[n*HD + lane] = lrelu(o);
}

// ---------- pooling ----------

__global__ void k_pool(const float* __restrict__ h2out, const int* __restrict__ batch,
                       float* __restrict__ gsum, unsigned* __restrict__ gmaxk, int* __restrict__ gcnt){
  __shared__ float ssum[NGR*HD];
  __shared__ unsigned smax[NGR*HD];
  __shared__ int scnt[NGR];
  int t = threadIdx.x;   // 256
  for (int i = t; i < NGR*HD; i += 256){ ssum[i] = 0.f; smax[i] = 0u; }
  if (t < NGR) scnt[t] = 0;
  __syncthreads();
  int wv = t >> 6, lane = t & 63;
  for (int n = blockIdx.x*4 + wv; n < NN; n += gridDim.x*4){
    int g = batch[n];
    float v = h2out[n*HD + lane];
    atomicAdd(&ssum[g*HD + lane], v);
    atomicMax(&smax[g*HD + lane], f2key(v));
    if (lane == 0) atomicAdd(&scnt[g], 1);
  }
  __syncthreads();
  for (int i = t; i < NGR*HD; i += 256){
    atomicAdd(&gsum[i], ssum[i]);
    atomicMax(&gmaxk[i], smax[i]);
  }
  if (t < NGR) atomicAdd(&gcnt[t], scnt[t]);
}

// ---------- final MLP + log_softmax ----------

__global__ void k_final(const float* __restrict__ gsum, const unsigned* __restrict__ gmaxk,
                        const int* __restrict__ gcnt,
                        const float* __restrict__ Wf1, const float* __restrict__ bf1,
                        const float* __restrict__ Wf2, const float* __restrict__ bf2,
                        float* __restrict__ out){
  int g = blockIdx.x, t = threadIdx.x;  // 64 threads
  __shared__ float gv[HD];
  __shared__ float f1[32];
  __shared__ float lg[NCL];
  int c = gcnt[g];
  float dn = fmaxf((float)c, 1.f);
  float mean = gsum[g*HD + t] / dn;
  float mx = (c > 0) ? key2f(gmaxk[g*HD + t]) : 0.f;
  gv[t] = mean + mx;
  __syncthreads();
  if (t < 32){
    float a = bf1[t];
#pragma unroll
    for (int k = 0; k < HD; ++k) a += gv[k] * Wf1[k*32 + t];
    f1[t] = a > 0.f ? a : 0.f;
  }
  __syncthreads();
  if (t < NCL){
    float a = bf2[t];
#pragma unroll
    for (int k = 0; k < 32; ++k) a += f1[k] * Wf2[k*NCL + t];
    lg[t] = a;
  }
  __syncthreads();
  if (t < NCL){
    float m = lg[0];
#pragma unroll
    for (int i = 1; i < NCL; ++i) m = fmaxf(m, lg[i]);
    float s = 0.f;
#pragma unroll
    for (int i = 0; i < NCL; ++i) s += expf(lg[i] - m);
    out[g*NCL + t] = lg[t] - m - logf(s);
  }
}

extern "C" void kernel_launch(void* const* d_in, const int* in_sizes, int n_in,
                              void* d_out, int out_size, void* d_ws, size_t ws_size,
                              hipStream_t stream) {
  const float* x   = (const float*)d_in[0];
  const int*   ei  = (const int*)d_in[1];
  const int*   bat = (const int*)d_in[2];
  const float* Wp  = (const float*)d_in[3];
  const float* bp  = (const float*)d_in[4];
  const float* W1  = (const float*)d_in[5];
  const float* as1 = (const float*)d_in[6];
  const float* ad1 = (const float*)d_in[7];
  const float* b1  = (const float*)d_in[8];
  const float* W2  = (const float*)d_in[9];
  const float* as2 = (const float*)d_in[10];
  const float* ad2 = (const float*)d_in[11];
  const float* b2  = (const float*)d_in[12];
  const float* Wf1 = (const float*)d_in[13];
  const float* bf1 = (const float*)d_in[14];
  const float* Wf2 = (const float*)d_in[15];
  const float* bf2 = (const float*)d_in[16];
  float* out = (float*)d_out;

  // ---- workspace layout (4-byte elements) ----
  char* base = (char*)d_ws;
  size_t o = 0;
  auto alloc = [&](size_t elems) -> char* {
    char* p = base + o*4;
    o += (elems + 63) & ~(size_t)63;   // 256B align
    return p;
  };
  float* h0     = (float*)alloc(3200000);      // [NN,64]  (reused as h2feat)
  float* h1feat = (float*)alloc(12800000);     // [NN,256] (reused: h2out in front)
  float* h1out  = (float*)alloc(12800000);     // [NN,256]
  float* a_s1   = (float*)alloc(200000);
  float* a_d1   = (float*)alloc(200000);
  float* a_s2   = (float*)alloc(50000);
  float* a_d2   = (float*)alloc(50000);
  int*   cnt    = (int*)alloc(50000);
  int*   off    = (int*)alloc(50001);
  int*   pos    = (int*)alloc(50000);
  int*   bsums  = (int*)alloc(256);
  int*   boffs  = (int*)alloc(256);
  int*   eids   = (int*)alloc(850000);
  float* gsum   = (float*)alloc(NGR*HD);       // these three contiguous -> one memset
  unsigned* gmaxk = (unsigned*)alloc(NGR*HD);
  int*   gcnt   = (int*)alloc(NGR);
  float* h2feat = h0;       // reuse (h0 dead after k_feat1)
  float* h2out  = h1feat;   // reuse (h1feat dead after k_gat1)

  const int NB = (NN + 255) / 256;       // 196
  const int EB = (ET + 255) / 256;       // 3321

  // CSR build
  hipMemsetAsync(cnt, 0, NN*sizeof(int), stream);
  k_hist<<<EB, 256, 0, stream>>>(ei, cnt);
  k_bsum<<<NB, 256, 0, stream>>>(cnt, bsums);
  k_boff<<<1, 64, 0, stream>>>(bsums, boffs, NB);
  k_off<<<NB, 256, 0, stream>>>(cnt, boffs, off, pos);
  k_scatter<<<EB, 256, 0, stream>>>(ei, pos, eids);

  // dense front-end
  k_proj<<<NN, 64, 0, stream>>>(x, Wp, bp, h0);
  k_feat1<<<NN, 256, 0, stream>>>(h0, W1, as1, ad1, h1feat, a_s1, a_d1);

  // GAT layer 1
  k_gat1<<<NN, 256, 0, stream>>>(h1feat, a_s1, a_d1, off, eids, ei, b1, h1out);

  // GAT layer 2
  k_feat2<<<NN, 64, 0, stream>>>(h1out, W2, as2, ad2, h2feat, a_s2, a_d2);
  k_gat2<<<NN, 64, 0, stream>>>(h2feat, a_s2, a_d2, off, eids, ei, b2, h2out);

  // pooling
  hipMemsetAsync(gsum, 0, (NGR*HD*2 + 64)*sizeof(int), stream);
  k_pool<<<256, 256, 0, stream>>>(h2out, bat, gsum, gmaxk, gcnt);

  // head MLP + log_softmax
  k_final<<<NGR, 64, 0, stream>>>(gsum, gmaxk, gcnt, Wf1, bf1, Wf2, bf2, out);
}

// Round 2
// 601.872 us; speedup vs baseline: 1.3280x; 1.3280x over previous
//
#include <hip/hip_runtime.h>
#include <math.h>

#define NN 50000
#define EE 800000
#define ET 850000    // EE + NN self loops
#define FIN 128
#define HD 64
#define NH 4
#define NGR 64
#define NCL 10
#define NEG 0.2f
#define MAXDEG 128

__device__ __forceinline__ float lrelu(float x){ return x > 0.f ? x : NEG * x; }

__device__ __forceinline__ float wsum(float v){
#pragma unroll
  for (int o = 32; o > 0; o >>= 1) v += __shfl_xor(v, o, 64);
  return v;
}
__device__ __forceinline__ float wmax(float v){
#pragma unroll
  for (int o = 32; o > 0; o >>= 1) v = fmaxf(v, __shfl_xor(v, o, 64));
  return v;
}
__device__ __forceinline__ int esrc(const int* ei, int e){ return e < EE ? ei[e] : e - EE; }
__device__ __forceinline__ int edst(const int* ei, int e){ return e < EE ? ei[EE + e] : e - EE; }

__device__ __forceinline__ unsigned f2key(float f){
  unsigned u = __float_as_uint(f);
  return (u & 0x80000000u) ? ~u : (u | 0x80000000u);
}
__device__ __forceinline__ float key2f(unsigned k){
  return (k & 0x80000000u) ? __uint_as_float(k & 0x7fffffffu) : __uint_as_float(~k);
}

// ---------- dense kernels (LDS-staged W, many nodes per block) ----------

#define PROJ_NPB 100
// h0 = relu(x @ W_proj + b_proj)   [NN,128]@[128,64]
__global__ __launch_bounds__(256) void k_proj(const float* __restrict__ x, const float* __restrict__ Wp,
                       const float* __restrict__ bp, float* __restrict__ h0){
  __shared__ float Ws[FIN*HD];     // 32KB
  __shared__ float xs[4][FIN];
  int t = threadIdx.x;
  for (int i = t; i < FIN*HD; i += 256) Ws[i] = Wp[i];
  int wv = t >> 6, lane = t & 63;
  float bj = bp[lane];
  int n0 = blockIdx.x * PROJ_NPB;
  int n1 = n0 + PROJ_NPB; if (n1 > NN) n1 = NN;
  for (int nb = n0; nb < n1; nb += 4){
    __syncthreads();
    for (int i = t; i < 4*FIN; i += 256){
      int q = i >> 7, k = i & (FIN-1);
      int nn = nb + q;
      if (nn < n1) xs[q][k] = x[(size_t)nn*FIN + k];
    }
    __syncthreads();
    int nn = nb + wv;
    if (nn < n1){
      float acc = bj;
#pragma unroll 8
      for (int k = 0; k < FIN; ++k) acc = fmaf(xs[wv][k], Ws[k*HD + lane], acc);
      h0[(size_t)nn*HD + lane] = fmaxf(acc, 0.f);
    }
  }
}

#define F1_NPB 100
// h1feat = h0 @ W1  [NN,64]@[64,256];  a_src1/a_dst1 per-head dots (head == wave)
__global__ __launch_bounds__(256) void k_feat1(const float* __restrict__ h0, const float* __restrict__ W1,
                        const float* __restrict__ as, const float* __restrict__ ad,
                        float* __restrict__ h1feat, float* __restrict__ a_s, float* __restrict__ a_d){
  __shared__ float Ws[HD*256];     // 64KB
  __shared__ float xs[4][HD];
  int t = threadIdx.x;
  for (int i = t; i < HD*256; i += 256) Ws[i] = W1[i];
  int wv = t >> 6, lane = t & 63;
  float asj = as[t], adj = ad[t];
  int n0 = blockIdx.x * F1_NPB;
  int n1 = n0 + F1_NPB; if (n1 > NN) n1 = NN;
  for (int nb = n0; nb < n1; nb += 4){
    __syncthreads();
    {
      int q = t >> 6, k = t & 63;
      int nn = nb + q;
      if (nn < n1) xs[q][k] = h0[(size_t)nn*HD + k];
    }
    __syncthreads();
    float a0=0.f, a1=0.f, a2=0.f, a3=0.f;
#pragma unroll 4
    for (int k = 0; k < HD; ++k){
      float w = Ws[k*256 + t];
      a0 = fmaf(w, xs[0][k], a0);
      a1 = fmaf(w, xs[1][k], a1);
      a2 = fmaf(w, xs[2][k], a2);
      a3 = fmaf(w, xs[3][k], a3);
    }
    float accs[4] = {a0, a1, a2, a3};
    int rem = n1 - nb;
#pragma unroll
    for (int q = 0; q < 4; ++q){
      if (q < rem){
        int nn = nb + q;
        h1feat[(size_t)nn*256 + t] = accs[q];
        float vs = wsum(accs[q] * asj);
        float vd = wsum(accs[q] * adj);
        if (lane == 0){ a_s[nn*NH + wv] = vs; a_d[nn*NH + wv] = vd; }
      }
    }
  }
}

#define F2_NPB 100
// h2feat = h1out @ W2  [NN,256]@[256,64];  a_src2/a_dst2 dots
__global__ __launch_bounds__(256) void k_feat2(const float* __restrict__ h1out, const float* __restrict__ W2,
                        const float* __restrict__ as, const float* __restrict__ ad,
                        float* __restrict__ h2feat, float* __restrict__ a_s, float* __restrict__ a_d){
  __shared__ float Ws[256*HD];     // 64KB
  __shared__ float xs[4][256];
  int t = threadIdx.x;
  for (int i = t; i < 256*HD; i += 256) Ws[i] = W2[i];
  int wv = t >> 6, lane = t & 63;
  float asl = as[lane], adl = ad[lane];
  int n0 = blockIdx.x * F2_NPB;
  int n1 = n0 + F2_NPB; if (n1 > NN) n1 = NN;
  for (int nb = n0; nb < n1; nb += 4){
    __syncthreads();
    for (int i = t; i < 4*256; i += 256){
      int q = i >> 8, k = i & 255;
      int nn = nb + q;
      if (nn < n1) xs[q][k] = h1out[(size_t)nn*256 + k];
    }
    __syncthreads();
    int nn = nb + wv;
    if (nn < n1){
      float acc = 0.f;
#pragma unroll 8
      for (int k = 0; k < 256; ++k) acc = fmaf(xs[wv][k], Ws[k*HD + lane], acc);
      float vs = wsum(acc * asl);
      float vd = wsum(acc * adl);
      h2feat[(size_t)nn*HD + lane] = acc;
      if (lane == 0){ a_s[nn] = vs; a_d[nn] = vd; }
    }
  }
}

// ---------- CSR build ----------

__global__ void k_hist(const int* __restrict__ ei, int* __restrict__ cnt){
  int e = blockIdx.x*256 + threadIdx.x;
  if (e < ET) atomicAdd(&cnt[edst(ei, e)], 1);
}

__global__ void k_bsum(const int* __restrict__ cnt, int* __restrict__ bsums){
  int b = blockIdx.x, t = threadIdx.x;
  int i = b*256 + t;
  int v = (i < NN) ? cnt[i] : 0;
  float s = wsum((float)v);
  __shared__ float ws4[4];
  if ((t & 63) == 0) ws4[t >> 6] = s;
  __syncthreads();
  if (t == 0) bsums[b] = (int)(ws4[0] + ws4[1] + ws4[2] + ws4[3] + 0.5f);
}

__global__ void k_boff(const int* __restrict__ bsums, int* __restrict__ boffs, int nb){
  if (threadIdx.x == 0){
    int r = 0;
    for (int b = 0; b < nb; ++b){ boffs[b] = r; r += bsums[b]; }
  }
}

__global__ void k_off(const int* __restrict__ cnt, const int* __restrict__ boffs,
                      int* __restrict__ off, int* __restrict__ pos){
  int b = blockIdx.x, t = threadIdx.x;
  int i = b*256 + t;
  __shared__ int s[256];
  int v = (i < NN) ? cnt[i] : 0;
  s[t] = v; __syncthreads();
  for (int d = 1; d < 256; d <<= 1){
    int xv = (t >= d) ? s[t-d] : 0;
    __syncthreads();
    s[t] += xv;
    __syncthreads();
  }
  int excl = s[t] - v;
  if (i < NN){ int o = boffs[b] + excl; off[i] = o; pos[i] = o; }
  if (i == NN - 1) off[NN] = boffs[b] + s[t];
}

// stores SRC node id directly (no edge-id indirection downstream)
__global__ void k_scatter(const int* __restrict__ ei, int* __restrict__ pos, int* __restrict__ csrc){
  int e = blockIdx.x*256 + threadIdx.x;
  if (e < ET){
    int d = edst(ei, e);
    int idx = atomicAdd(&pos[d], 1);
    csrc[idx] = esrc(ei, e);
  }
}

// ---------- GAT aggregation ----------
// per-edge exp weights computed ONCE (lane-strided), broadcast via shfl (v_readlane)

__global__ __launch_bounds__(256) void k_gat1(const float* __restrict__ h1feat, const float* __restrict__ a_s,
                       const float* __restrict__ a_d, const int* __restrict__ off,
                       const int* __restrict__ csrc, const float* __restrict__ b1,
                       float* __restrict__ h1out){
  int n = blockIdx.x;
  int h = threadIdx.x >> 6, lane = threadIdx.x & 63;   // wave == head
  int e0 = off[n], e1 = off[n+1], deg = e1 - e0;
  float adst = a_d[n*NH + h];
  float bv = b1[h*HD + lane];
  float acc = 0.f, inv;
  if (deg <= MAXDEG){
    int sA = 0, sB = 0;
    float alA = -3.0e38f, alB = -3.0e38f;
    if (lane < deg){
      sA = csrc[e0 + lane];
      alA = lrelu(a_s[sA*NH + h] + adst);
    }
    if (64 + lane < deg){
      sB = csrc[e0 + 64 + lane];
      alB = lrelu(a_s[sB*NH + h] + adst);
    }
    float m = wmax(fmaxf(alA, alB));
    float wA = (lane < deg)      ? __expf(alA - m) : 0.f;
    float wB = (64 + lane < deg) ? __expf(alB - m) : 0.f;
    float se = wsum(wA + wB);
    inv = 1.f / (se + 1e-16f);
    const float* base = h1feat + h*HD + lane;
    int idx = 0;
    for (; idx + 4 <= deg; idx += 4){
      int i0 = idx, i1 = idx+1, i2 = idx+2, i3 = idx+3;
      int s0 = (i0 < 64) ? __shfl(sA, i0, 64) : __shfl(sB, i0-64, 64);
      int s1 = (i1 < 64) ? __shfl(sA, i1, 64) : __shfl(sB, i1-64, 64);
      int s2 = (i2 < 64) ? __shfl(sA, i2, 64) : __shfl(sB, i2-64, 64);
      int s3 = (i3 < 64) ? __shfl(sA, i3, 64) : __shfl(sB, i3-64, 64);
      float w0 = (i0 < 64) ? __shfl(wA, i0, 64) : __shfl(wB, i0-64, 64);
      float w1 = (i1 < 64) ? __shfl(wA, i1, 64) : __shfl(wB, i1-64, 64);
      float w2 = (i2 < 64) ? __shfl(wA, i2, 64) : __shfl(wB, i2-64, 64);
      float w3 = (i3 < 64) ? __shfl(wA, i3, 64) : __shfl(wB, i3-64, 64);
      float v0 = base[(size_t)s0*256];
      float v1 = base[(size_t)s1*256];
      float v2 = base[(size_t)s2*256];
      float v3 = base[(size_t)s3*256];
      acc += v0*w0 + v1*w1 + v2*w2 + v3*w3;
    }
    for (; idx < deg; ++idx){
      int s = (idx < 64) ? __shfl(sA, idx, 64) : __shfl(sB, idx-64, 64);
      float w = (idx < 64) ? __shfl(wA, idx, 64) : __shfl(wB, idx-64, 64);
      acc += base[(size_t)s*256] * w;
    }
  } else {
    // fallback (never expected for this graph): recompute per lane
    float m = -3.0e38f;
    for (int i = e0 + lane; i < e1; i += 64){
      int s = csrc[i];
      m = fmaxf(m, lrelu(a_s[s*NH + h] + adst));
    }
    m = wmax(m);
    float se = 0.f;
    for (int i = e0 + lane; i < e1; i += 64){
      int s = csrc[i];
      se += __expf(lrelu(a_s[s*NH + h] + adst) - m);
    }
    se = wsum(se);
    inv = 1.f / (se + 1e-16f);
    for (int i = e0; i < e1; ++i){
      int s = csrc[i];
      float w = __expf(lrelu(a_s[s*NH + h] + adst) - m);
      acc += h1feat[(size_t)s*256 + h*HD + lane] * w;
    }
  }
  float o = acc*inv + bv;
  h1out[(size_t)n*256 + h*HD + lane] = lrelu(o);
}

__global__ __launch_bounds__(256) void k_gat2(const float* __restrict__ h2feat, const float* __restrict__ a_s,
                       const float* __restrict__ a_d, const int* __restrict__ off,
                       const int* __restrict__ csrc, const float* __restrict__ b2,
                       float* __restrict__ h2out){
  int wv = threadIdx.x >> 6, lane = threadIdx.x & 63;
  int n = blockIdx.x*4 + wv;      // wave == node
  if (n >= NN) return;
  int e0 = off[n], e1 = off[n+1], deg = e1 - e0;
  float adst = a_d[n];
  float acc = 0.f, inv;
  if (deg <= MAXDEG){
    int sA = 0, sB = 0;
    float alA = -3.0e38f, alB = -3.0e38f;
    if (lane < deg){
      sA = csrc[e0 + lane];
      alA = lrelu(a_s[sA] + adst);
    }
    if (64 + lane < deg){
      sB = csrc[e0 + 64 + lane];
      alB = lrelu(a_s[sB] + adst);
    }
    float m = wmax(fmaxf(alA, alB));
    float wA = (lane < deg)      ? __expf(alA - m) : 0.f;
    float wB = (64 + lane < deg) ? __expf(alB - m) : 0.f;
    float se = wsum(wA + wB);
    inv = 1.f / (se + 1e-16f);
    int idx = 0;
    for (; idx + 4 <= deg; idx += 4){
      int i0 = idx, i1 = idx+1, i2 = idx+2, i3 = idx+3;
      int s0 = (i0 < 64) ? __shfl(sA, i0, 64) : __shfl(sB, i0-64, 64);
      int s1 = (i1 < 64) ? __shfl(sA, i1, 64) : __shfl(sB, i1-64, 64);
      int s2 = (i2 < 64) ? __shfl(sA, i2, 64) : __shfl(sB, i2-64, 64);
      int s3 = (i3 < 64) ? __shfl(sA, i3, 64) : __shfl(sB, i3-64, 64);
      float w0 = (i0 < 64) ? __shfl(wA, i0, 64) : __shfl(wB, i0-64, 64);
      float w1 = (i1 < 64) ? __shfl(wA, i1, 64) : __shfl(wB, i1-64, 64);
      float w2 = (i2 < 64) ? __shfl(wA, i2, 64) : __shfl(wB, i2-64, 64);
      float w3 = (i3 < 64) ? __shfl(wA, i3, 64) : __shfl(wB, i3-64, 64);
      float v0 = h2feat[(size_t)s0*HD + lane];
      float v1 = h2feat[(size_t)s1*HD + lane];
      float v2 = h2feat[(size_t)s2*HD + lane];
      float v3 = h2feat[(size_t)s3*HD + lane];
      acc += v0*w0 + v1*w1 + v2*w2 + v3*w3;
    }
    for (; idx < deg; ++idx){
      int s = (idx < 64) ? __shfl(sA, idx, 64) : __shfl(sB, idx-64, 64);
      float w = (idx < 64) ? __shfl(wA, idx, 64) : __shfl(wB, idx-64, 64);
      acc += h2feat[(size_t)s*HD + lane] * w;
    }
  } else {
    float m = -3.0e38f;
    for (int i = e0 + lane; i < e1; i += 64){
      int s = csrc[i];
      m = fmaxf(m, lrelu(a_s[s] + adst));
    }
    m = wmax(m);
    float se = 0.f;
    for (int i = e0 + lane; i < e1; i += 64){
      int s = csrc[i];
      se += __expf(lrelu(a_s[s] + adst) - m);
    }
    se = wsum(se);
    inv = 1.f / (se + 1e-16f);
    for (int i = e0; i < e1; ++i){
      int s = csrc[i];
      acc += h2feat[(size_t)s*HD + lane] * __expf(lrelu(a_s[s] + adst) - m);
    }
  }
  float o = acc*inv + b2[lane];
  h2out[(size_t)n*HD + lane] = lrelu(o);
}

// ---------- pooling ----------

__global__ void k_pool(const float* __restrict__ h2out, const int* __restrict__ batch,
                       float* __restrict__ gsum, unsigned* __restrict__ gmaxk, int* __restrict__ gcnt){
  __shared__ float ssum[NGR*HD];
  __shared__ unsigned smax[NGR*HD];
  __shared__ int scnt[NGR];
  int t = threadIdx.x;   // 256
  for (int i = t; i < NGR*HD; i += 256){ ssum[i] = 0.f; smax[i] = 0u; }
  if (t < NGR) scnt[t] = 0;
  __syncthreads();
  int wv = t >> 6, lane = t & 63;
  for (int n = blockIdx.x*4 + wv; n < NN; n += gridDim.x*4){
    int g = batch[n];
    float v = h2out[(size_t)n*HD + lane];
    atomicAdd(&ssum[g*HD + lane], v);
    atomicMax(&smax[g*HD + lane], f2key(v));
    if (lane == 0) atomicAdd(&scnt[g], 1);
  }
  __syncthreads();
  for (int i = t; i < NGR*HD; i += 256){
    atomicAdd(&gsum[i], ssum[i]);
    atomicMax(&gmaxk[i], smax[i]);
  }
  if (t < NGR) atomicAdd(&gcnt[t], scnt[t]);
}

// ---------- final MLP + log_softmax ----------

__global__ void k_final(const float* __restrict__ gsum, const unsigned* __restrict__ gmaxk,
                        const int* __restrict__ gcnt,
                        const float* __restrict__ Wf1, const float* __restrict__ bf1,
                        const float* __restrict__ Wf2, const float* __restrict__ bf2,
                        float* __restrict__ out){
  int g = blockIdx.x, t = threadIdx.x;  // 64 threads
  __shared__ float gv[HD];
  __shared__ float f1[32];
  __shared__ float lg[NCL];
  int c = gcnt[g];
  float dn = fmaxf((float)c, 1.f);
  float mean = gsum[g*HD + t] / dn;
  float mx = (c > 0) ? key2f(gmaxk[g*HD + t]) : 0.f;
  gv[t] = mean + mx;
  __syncthreads();
  if (t < 32){
    float a = bf1[t];
#pragma unroll
    for (int k = 0; k < HD; ++k) a += gv[k] * Wf1[k*32 + t];
    f1[t] = a > 0.f ? a : 0.f;
  }
  __syncthreads();
  if (t < NCL){
    float a = bf2[t];
#pragma unroll
    for (int k = 0; k < 32; ++k) a += f1[k] * Wf2[k*NCL + t];
    lg[t] = a;
  }
  __syncthreads();
  if (t < NCL){
    float m = lg[0];
#pragma unroll
    for (int i = 1; i < NCL; ++i) m = fmaxf(m, lg[i]);
    float s = 0.f;
#pragma unroll
    for (int i = 0; i < NCL; ++i) s += expf(lg[i] - m);
    out[g*NCL + t] = lg[t] - m - logf(s);
  }
}

extern "C" void kernel_launch(void* const* d_in, const int* in_sizes, int n_in,
                              void* d_out, int out_size, void* d_ws, size_t ws_size,
                              hipStream_t stream) {
  const float* x   = (const float*)d_in[0];
  const int*   ei  = (const int*)d_in[1];
  const int*   bat = (const int*)d_in[2];
  const float* Wp  = (const float*)d_in[3];
  const float* bp  = (const float*)d_in[4];
  const float* W1  = (const float*)d_in[5];
  const float* as1 = (const float*)d_in[6];
  const float* ad1 = (const float*)d_in[7];
  const float* b1  = (const float*)d_in[8];
  const float* W2  = (const float*)d_in[9];
  const float* as2 = (const float*)d_in[10];
  const float* ad2 = (const float*)d_in[11];
  const float* b2  = (const float*)d_in[12];
  const float* Wf1 = (const float*)d_in[13];
  const float* bf1 = (const float*)d_in[14];
  const float* Wf2 = (const float*)d_in[15];
  const float* bf2 = (const float*)d_in[16];
  float* out = (float*)d_out;

  char* base = (char*)d_ws;
  size_t o = 0;
  auto alloc = [&](size_t elems) -> char* {
    char* p = base + o*4;
    o += (elems + 63) & ~(size_t)63;
    return p;
  };
  float* h0     = (float*)alloc(3200000);      // [NN,64]  (reused as h2feat)
  float* h1feat = (float*)alloc(12800000);     // [NN,256] (front reused as h2out)
  float* h1out  = (float*)alloc(12800000);     // [NN,256]
  float* a_s1   = (float*)alloc(200000);
  float* a_d1   = (float*)alloc(200000);
  float* a_s2   = (float*)alloc(50000);
  float* a_d2   = (float*)alloc(50000);
  int*   cnt    = (int*)alloc(50000);
  int*   off    = (int*)alloc(50001);
  int*   pos    = (int*)alloc(50000);
  int*   bsums  = (int*)alloc(256);
  int*   boffs  = (int*)alloc(256);
  int*   csrc   = (int*)alloc(850000);
  float* gsum   = (float*)alloc(NGR*HD);
  unsigned* gmaxk = (unsigned*)alloc(NGR*HD);
  int*   gcnt   = (int*)alloc(NGR);
  float* h2feat = h0;
  float* h2out  = h1feat;

  const int NB = (NN + 255) / 256;
  const int EB = (ET + 255) / 256;

  // CSR build
  hipMemsetAsync(cnt, 0, NN*sizeof(int), stream);
  k_hist<<<EB, 256, 0, stream>>>(ei, cnt);
  k_bsum<<<NB, 256, 0, stream>>>(cnt, bsums);
  k_boff<<<1, 64, 0, stream>>>(bsums, boffs, NB);
  k_off<<<NB, 256, 0, stream>>>(cnt, boffs, off, pos);
  k_scatter<<<EB, 256, 0, stream>>>(ei, pos, csrc);

  // dense front-end
  k_proj<<<(NN + PROJ_NPB - 1)/PROJ_NPB, 256, 0, stream>>>(x, Wp, bp, h0);
  k_feat1<<<(NN + F1_NPB - 1)/F1_NPB, 256, 0, stream>>>(h0, W1, as1, ad1, h1feat, a_s1, a_d1);

  // GAT layer 1
  k_gat1<<<NN, 256, 0, stream>>>(h1feat, a_s1, a_d1, off, csrc, b1, h1out);

  // GAT layer 2
  k_feat2<<<(NN + F2_NPB - 1)/F2_NPB, 256, 0, stream>>>(h1out, W2, as2, ad2, h2feat, a_s2, a_d2);
  k_gat2<<<(NN + 3)/4, 256, 0, stream>>>(h2feat, a_s2, a_d2, off, csrc, b2, h2out);

  // pooling
  hipMemsetAsync(gsum, 0, (NGR*HD*2 + 64)*sizeof(int), stream);
  k_pool<<<256, 256, 0, stream>>>(h2out, bat, gsum, gmaxk, gcnt);

  // head MLP + log_softmax
  k_final<<<NGR, 64, 0, stream>>>(gsum, gmaxk, gcnt, Wf1, bf1, Wf2, bf2, out);
}